// Round 5
// baseline (416.992 us; speedup 1.0000x reference)
//
#include <hip/hip_runtime.h>

typedef unsigned short u16;
typedef unsigned int u32;
typedef __attribute__((ext_vector_type(4))) float f32x4;
typedef __attribute__((ext_vector_type(8))) short s16x8;
typedef __attribute__((ext_vector_type(4))) unsigned int u32x4;

#define DEVI static __device__ __forceinline__

// B=2, S=2048, E=2048, H=16, D=128, MP=4, local=512; qkv cols: [q(512) v(512) k(512)] x4
// k-rope fused into QKV-GEMM epilogue; q-rope (+ (1/sqrt(128))*log2(e) scale) fused into
// attention prologue; softmax in exp2 domain.

#define ROPE_C (-13.287712379549449f / 32.0f)  // -log2(10000)/32
#define QSCALE 0.12751743f                     // log2(e)/sqrt(128)

DEVI u16 f2bf(float f) {
  u32 u = __float_as_uint(f);
  return (u16)((u + 0x7FFFu + ((u >> 16) & 1u)) >> 16);  // round-to-nearest-even
}
DEVI float bf2f(u16 h) { return __uint_as_float(((u32)h) << 16); }

DEVI void async_copy16(const u16* g, u16* l) {
  // dest = wave-uniform LDS base + lane*16 (gfx950 global_load_lds_dwordx4)
  __builtin_amdgcn_global_load_lds((__attribute__((address_space(1))) void*)g,
                                   (__attribute__((address_space(3))) void*)l, 16, 0, 0);
}

// fused fp32->bf16 cast of all three inputs
__global__ __launch_bounds__(256) void cast3_kernel(
    const float* __restrict__ s0, u16* __restrict__ d0, int n0,
    const float* __restrict__ s1, u16* __restrict__ d1, int n1,
    const float* __restrict__ s2, u16* __restrict__ d2, int n2) {
  int i = blockIdx.x * 256 + threadIdx.x;
  const float* s;
  u16* d;
  if (i < n0) {
    s = s0; d = d0;
  } else if (i < n0 + n1) {
    s = s1; d = d1; i -= n0;
  } else if (i < n0 + n1 + n2) {
    s = s2; d = d2; i -= n0 + n1;
  } else {
    return;
  }
  const float4 v = ((const float4*)s)[i];
  ushort4 o;
  o.x = f2bf(v.x); o.y = f2bf(v.y); o.z = f2bf(v.z); o.w = f2bf(v.w);
  ((ushort4*)d)[i] = o;
}

// C[m,n] = sum_k A[m,k]*B[n,k]; A,B row-major bf16, K contiguous (B^T GEMM).
// 128x128 tile, BK=32, 4 waves 2x2 of 64x64, 16x16x32 MFMA, 4x4 frags/wave.
// R4 structure (best measured, 136.5us QKV): A,B staged through 3-deep LDS via
// global_load_lds w16, XOR-swizzled, vmcnt(4) + raw s_barrier in steady state,
// 3 blocks/CU (cross-block overlap hides the barrier drains). Inline epilogue.
// EPI=0: C fp32 store. EPI=1: scatter qkv -> q[B,H,S,D], k(roped)[B,H,S,D], v^T[B,H,D,S].
template <int EPI>
__global__ __launch_bounds__(256, 3) void gemm_bt_kernel(
    const u16* __restrict__ A, const u16* __restrict__ Bm, int K, int N,
    float* __restrict__ C, u16* __restrict__ qo, u16* __restrict__ ko, u16* __restrict__ vo) {
  __shared__ __attribute__((aligned(16))) u16 As[3][128 * 32];  // 8KB each
  __shared__ __attribute__((aligned(16))) u16 Bs[3][128 * 32];  // 8KB each
  const int tid = threadIdx.x;
  const int w = tid >> 6, lane = tid & 63;
  const int quad = lane >> 4, l16 = lane & 15;
  const int wrow = (w >> 1) * 64, wcol = (w & 1) * 64;
  const long tileM = (long)blockIdx.y * 128;
  const long tileN = (long)blockIdx.x * 128;

  f32x4 acc[4][4];
#pragma unroll
  for (int i = 0; i < 4; ++i)
#pragma unroll
    for (int j = 0; j < 4; ++j) acc[i][j] = f32x4{0.f, 0.f, 0.f, 0.f};

  // staging: wave w covers tile rows [w*32, w*32+32) in two 16-row chunks.
  const u16* aptr[2];
  const u16* bptr[2];
  int ldso[2];
#pragma unroll
  for (int c = 0; c < 2; ++c) {
    const int r0 = (w * 2 + c) * 16;
    const int row = r0 + (lane >> 2);
    const int colsw = (((lane & 3) ^ ((row >> 1) & 3)) << 3);
    aptr[c] = A + (tileM + row) * (long)K + colsw;
    bptr[c] = Bm + (tileN + row) * (long)K + colsw;
    ldso[c] = r0 * 32;
  }

  auto stage = [&](int k0, int buf) {
#pragma unroll
    for (int c = 0; c < 2; ++c) {
      async_copy16(aptr[c] + k0, &As[buf][ldso[c]]);
      async_copy16(bptr[c] + k0, &Bs[buf][ldso[c]]);
    }
  };

  stage(0, 0);
  stage(32, 1);

  const int psw = (quad ^ ((l16 >> 1) & 3)) << 3;  // read-side swizzle (lane-constant)

  int bt = 0;
  for (int k0 = 0; k0 < K; k0 += 32) {
    if (k0 + 32 < K)
      __builtin_amdgcn_s_waitcnt(0x0f74);  // vmcnt(4): tile t landed, t+1 in flight
    else
      __builtin_amdgcn_s_waitcnt(0x0f70);  // last tile: vmcnt(0)
    __builtin_amdgcn_s_barrier();          // raw barrier: no compiler-forced drain
    if (k0 + 64 < K) stage(k0 + 64, bt == 0 ? 2 : bt - 1);

    s16x8 af[4], bfr[4];
#pragma unroll
    for (int i = 0; i < 4; ++i)
      af[i] = *(const s16x8*)(&As[bt][(wrow + i * 16 + l16) * 32 + psw]);
#pragma unroll
    for (int j = 0; j < 4; ++j)
      bfr[j] = *(const s16x8*)(&Bs[bt][(wcol + j * 16 + l16) * 32 + psw]);
#pragma unroll
    for (int i = 0; i < 4; ++i)
#pragma unroll
      for (int j = 0; j < 4; ++j)
        acc[i][j] = __builtin_amdgcn_mfma_f32_16x16x32_bf16(af[i], bfr[j], acc[i][j], 0, 0, 0);
    bt = bt == 2 ? 0 : bt + 1;
  }

  // ---- inline epilogue (single call site; acc stays in registers) ----
  const int b = (int)(tileM >> 11);  // 128-row tile never straddles batch
#pragma unroll
  for (int i = 0; i < 4; ++i) {
#pragma unroll
    for (int j = 0; j < 4; ++j) {
      const int rowb = (int)((tileM + wrow + i * 16 + quad * 4) & 2047);  // s of reg 0
      if (EPI == 0) {
#pragma unroll
        for (int r = 0; r < 4; ++r) {
          const long row = tileM + wrow + i * 16 + quad * 4 + r;
          C[row * N + tileN + wcol + j * 16 + l16] = acc[i][j][r];
        }
      } else {
        const long col0 = tileN + wcol + j * 16;  // wave-uniform base col of this frag
        const int mp = (int)(col0 / 1536);
        const int cc0 = (int)(col0 - (long)mp * 1536);
        const int part = cc0 >> 9;     // 0:q 1:v 2:k (uniform per frag)
        const int idx0 = cc0 & 511;
        const int head = mp * 4 + (idx0 >> 7);
        const int dim0 = idx0 & 127;
        const int dim = dim0 + l16;
        const long bh = (long)(b * 16 + head);
        if (part == 1) {
#pragma unroll
          for (int r = 0; r < 4; ++r)
            vo[(bh * 128 + dim) * 2048 + rowb + r] = f2bf(acc[i][j][r]);  // v^T
        } else {
          float y[4];
          if (part == 2 && dim0 < 64) {
            // k-rope: pair partner is adjacent lane (col parity == l16 parity)
            const int jj = dim >> 1;
            const float inv = exp2f((float)jj * ROPE_C);
#pragma unroll
            for (int r = 0; r < 4; ++r) {
              const float v = acc[i][j][r];
              const float pv = __shfl_xor(v, 1, 64);
              const float ang = (float)(rowb + r) * inv;
              const float sn = __sinf(ang), cs = __cosf(ang);
              y[r] = (l16 & 1) ? (v * cs + pv * sn) : (v * cs - pv * sn);
            }
          } else {
#pragma unroll
            for (int r = 0; r < 4; ++r) y[r] = acc[i][j][r];
          }
          u16* dst = (part == 0) ? qo : ko;
#pragma unroll
          for (int r = 0; r < 4; ++r)
            dst[(bh * 2048 + rowb + r) * 128 + dim] = f2bf(y[r]);
        }
      }
    }
  }
}

// Flash attention v5: 32 q-rows per wave (two 16-row B-frag groups). Block = 128 q
// rows (4 waves x 2x16), 32-key tiles, 3-deep LDS ring + counted vmcnt(4).
// Rationale (R4 post-mortem): inner loop was LDS-issue-bound -- 16 ds_read_b128 vs
// 16 MFMA per tile per wave. Two Q-groups share every K-frag and V-frag read:
// 32 MFMA : 16 b128 reads, halving LDS cost per q-row; K/V DMA per q-row also halves.
// Wave-uniform group-skip: a group with no unmasked keys in this tile skips
// QK/softmax/PV entirely (act0 => act1 since group0 rows < group1 rows).
// Zero-shuffle P path (permuted K staging), setprio (T5), defer-max THR=8 (T13),
// per-group in-lane softmax (2 shfl per group). PV = V^T*P -> out^T; ushort4 stores.
// Grid 512 = 32 bh x 16 qtiles, heavy-first; 2 blocks/CU (VGPR ~200).
__global__ __launch_bounds__(256, 2) void attn_kernel(
    const u16* __restrict__ q, const u16* __restrict__ k,
    const u16* __restrict__ vT, u16* __restrict__ out) {
  __shared__ __attribute__((aligned(16))) u16 Ks[3][32 * 128];  // 8KB each
  __shared__ __attribute__((aligned(16))) u16 Vs[3][128 * 32];  // 8KB each
  const int tid = threadIdx.x;
  const int w = tid >> 6, lane = tid & 63;
  const int quad = lane >> 4, l16 = lane & 15;
  const int qt = 15 - (blockIdx.x >> 5);  // heavy tiles dispatched first
  const int bh = blockIdx.x & 31;
  const int qb0 = qt * 128 + w * 16;       // group 0 base q-row
  const int qb1 = qb0 + 64;                // group 1 base q-row

  const u16* qp = q + ((long)bh * 2048 + qb0) * 128;
  const u16* kp = k + (long)bh * 2048 * 128;
  const u16* vp = vT + (long)bh * 128 * 2048;

  // Q B-frags for both groups: Q[n=l16][kdim = c*32 + quad*8 + j], roped + scaled
  s16x8 qf[2][4];
#pragma unroll
  for (int qg = 0; qg < 2; ++qg) {
    const float spos = (float)((qg ? qb1 : qb0) + l16);
    const u16* qpg = qp + (qg ? 64 * 128 : 0);
#pragma unroll
    for (int c = 0; c < 4; ++c) {
      const s16x8 raw = *(const s16x8*)(qpg + l16 * 128 + c * 32 + quad * 8);
      s16x8 ov;
      if (c < 2) {  // dims < 64: rotate pairs (in-lane: 2m, 2m+1)
#pragma unroll
        for (int m = 0; m < 4; ++m) {
          const int jj = c * 16 + quad * 4 + m;
          const float inv = exp2f((float)jj * ROPE_C);
          const float ang = spos * inv;
          const float sn = __sinf(ang), cs = __cosf(ang);
          const float x0 = bf2f((u16)raw[2 * m]), x1 = bf2f((u16)raw[2 * m + 1]);
          ov[2 * m] = (short)f2bf((x0 * cs - x1 * sn) * QSCALE);
          ov[2 * m + 1] = (short)f2bf((x1 * cs + x0 * sn) * QSCALE);
        }
      } else {      // dims >= 64: pass-through, scale only
#pragma unroll
        for (int e = 0; e < 8; ++e) ov[e] = (short)f2bf(bf2f((u16)raw[e]) * QSCALE);
      }
      qf[qg][c] = ov;
    }
  }

  f32x4 acc[2][8];  // out^T per group: acc[qg][dd] rows = dims dd*16+quad*4+r
#pragma unroll
  for (int qg = 0; qg < 2; ++qg)
#pragma unroll
    for (int d = 0; d < 8; ++d) acc[qg][d] = f32x4{0.f, 0.f, 0.f, 0.f};
  float mrun0 = -1e30f, lrun0 = 0.f;
  float mrun1 = -1e30f, lrun1 = 0.f;

  // stage one 32-key tile: wave w stages LDS K-rows [w*8,w*8+8) and V dims
  // [w*32,w*32+32); exactly 4 async DMAs per wave per tile (vmcnt is per-wave).
  // K rows PERMUTED: LDS row rr holds global key ((rr>>2)&3)*8+((rr>>4)&1)*4+(rr&3).
  auto stage = [&](int k0, int buf) {
    const int ko = lane >> 4, cl = lane & 15;
#pragma unroll
    for (int i = 0; i < 2; ++i) {
      const int keyt = w * 8 + i * 4;
      const int rr = keyt + ko;  // LDS row this lane fills
      const int sk = ((rr >> 2) & 3) * 8 + ((rr >> 4) & 1) * 4 + (rr & 3);
      async_copy16(kp + (long)(k0 + sk) * 128 + ((cl ^ (rr & 15)) << 3),
                   &Ks[buf][keyt * 128]);
    }
    const int ld = lane >> 2, c4 = lane & 3;
#pragma unroll
    for (int i = 0; i < 2; ++i) {
      const int db = w * 32 + i * 16;
      const int d = db + ld;
      async_copy16(vp + (long)d * 2048 + k0 + ((c4 ^ ((d >> 1) & 3)) << 3),
                   &Vs[buf][db * 32]);
    }
  };

  const int nt = 4 * qt + 4;  // block covers keys [0, 128*qt+128)
  stage(0, 0);
  stage(32, 1);

  int bt = 0;
  for (int t = 0; t < nt; ++t) {
    const int k0 = t * 32;
    if (t + 1 < nt)
      __builtin_amdgcn_s_waitcnt(0x0f74);  // vmcnt(4): tile t landed, t+1 in flight
    else
      __builtin_amdgcn_s_waitcnt(0x0f70);  // last tile: vmcnt(0)
    __builtin_amdgcn_s_barrier();          // all waves' tile-t DMA done; buf t-1 free
    if (t + 2 < nt) stage(k0 + 64, bt == 0 ? 2 : bt - 1);
    const u16* Ksc = Ks[bt];
    const u16* Vsc = Vs[bt];
    bt = bt == 2 ? 0 : bt + 1;

    // wave-uniform group activity: group g active iff tile has an unmasked key
    // for some row of g (k0 <= base+15). act0 implies act1.
    const bool act1 = (k0 <= qb1 + 15);
    const bool act0 = (k0 <= qb0 + 15);
    if (!act1) continue;  // barriers/staging already done; nothing to compute

    // S^T = K*Q^T: sc[qg][g] reg r at lane-quad u holds key k0+u*8+g*4+r (permuted
    // staging), col = q-row. Each kf read feeds 2 (or 1) groups' MFMAs.
    f32x4 sc0[2], sc1[2];
    sc0[0] = f32x4{0.f, 0.f, 0.f, 0.f};
    sc0[1] = f32x4{0.f, 0.f, 0.f, 0.f};
    sc1[0] = f32x4{0.f, 0.f, 0.f, 0.f};
    sc1[1] = f32x4{0.f, 0.f, 0.f, 0.f};
    __builtin_amdgcn_s_setprio(1);
#pragma unroll
    for (int c = 0; c < 4; ++c) {
      const s16x8 kf0 = *(const s16x8*)(
          &Ksc[(0 * 16 + l16) * 128 + ((((c << 2) + quad) ^ l16) << 3)]);
      const s16x8 kf1 = *(const s16x8*)(
          &Ksc[(1 * 16 + l16) * 128 + ((((c << 2) + quad) ^ l16) << 3)]);
      if (act0) {
        sc0[0] = __builtin_amdgcn_mfma_f32_16x16x32_bf16(kf0, qf[0][c], sc0[0], 0, 0, 0);
        sc0[1] = __builtin_amdgcn_mfma_f32_16x16x32_bf16(kf1, qf[0][c], sc0[1], 0, 0, 0);
      }
      sc1[0] = __builtin_amdgcn_mfma_f32_16x16x32_bf16(kf0, qf[1][c], sc1[0], 0, 0, 0);
      sc1[1] = __builtin_amdgcn_mfma_f32_16x16x32_bf16(kf1, qf[1][c], sc1[1], 0, 0, 0);
    }
    __builtin_amdgcn_s_setprio(0);

    // ---- group 1 (always active here): mask, softmax, pack ----
    if (k0 + 31 > qb1) {
      const int qrow = qb1 + l16;
#pragma unroll
      for (int g = 0; g < 2; ++g) {
        const int keyb = k0 + quad * 8 + g * 4;  // permuted key id of reg 0
#pragma unroll
        for (int r = 0; r < 4; ++r)
          if (keyb + r > qrow) sc1[g][r] = -1e30f;
      }
    }
    float mx1 = fmaxf(fmaxf(fmaxf(sc1[0][0], sc1[0][1]), fmaxf(sc1[0][2], sc1[0][3])),
                      fmaxf(fmaxf(sc1[1][0], sc1[1][1]), fmaxf(sc1[1][2], sc1[1][3])));
    mx1 = fmaxf(mx1, __shfl_xor(mx1, 16, 64));
    mx1 = fmaxf(mx1, __shfl_xor(mx1, 32, 64));
    if (__any(mx1 > mrun1 + 8.f)) {
      const float mnew = fmaxf(mrun1, mx1);
      const float alpha = exp2f(mrun1 - mnew);
      mrun1 = mnew;
      lrun1 *= alpha;
#pragma unroll
      for (int d = 0; d < 8; ++d)
#pragma unroll
        for (int r = 0; r < 4; ++r) acc[1][d][r] *= alpha;
    }
    float p1[2][4];
    float sm1 = 0.f;
#pragma unroll
    for (int g = 0; g < 2; ++g)
#pragma unroll
      for (int r = 0; r < 4; ++r) { p1[g][r] = exp2f(sc1[g][r] - mrun1); sm1 += p1[g][r]; }
    sm1 += __shfl_xor(sm1, 16, 64);
    sm1 += __shfl_xor(sm1, 32, 64);
    lrun1 += sm1;
    u32 pk1[2][2];
#pragma unroll
    for (int g = 0; g < 2; ++g) {
      pk1[g][0] = (u32)f2bf(p1[g][0]) | ((u32)f2bf(p1[g][1]) << 16);
      pk1[g][1] = (u32)f2bf(p1[g][2]) | ((u32)f2bf(p1[g][3]) << 16);
    }
    const u32x4 pw1 = {pk1[0][0], pk1[0][1], pk1[1][0], pk1[1][1]};
    const s16x8 pf1 = __builtin_bit_cast(s16x8, pw1);

    // ---- group 0 (active on early tiles): mask, softmax, pack ----
    s16x8 pf0;
    if (act0) {
      if (k0 + 31 > qb0) {
        const int qrow = qb0 + l16;
#pragma unroll
        for (int g = 0; g < 2; ++g) {
          const int keyb = k0 + quad * 8 + g * 4;
#pragma unroll
          for (int r = 0; r < 4; ++r)
            if (keyb + r > qrow) sc0[g][r] = -1e30f;
        }
      }
      float mx0 = fmaxf(fmaxf(fmaxf(sc0[0][0], sc0[0][1]), fmaxf(sc0[0][2], sc0[0][3])),
                        fmaxf(fmaxf(sc0[1][0], sc0[1][1]), fmaxf(sc0[1][2], sc0[1][3])));
      mx0 = fmaxf(mx0, __shfl_xor(mx0, 16, 64));
      mx0 = fmaxf(mx0, __shfl_xor(mx0, 32, 64));
      if (__any(mx0 > mrun0 + 8.f)) {
        const float mnew = fmaxf(mrun0, mx0);
        const float alpha = exp2f(mrun0 - mnew);
        mrun0 = mnew;
        lrun0 *= alpha;
#pragma unroll
        for (int d = 0; d < 8; ++d)
#pragma unroll
          for (int r = 0; r < 4; ++r) acc[0][d][r] *= alpha;
      }
      float p0[2][4];
      float sm0 = 0.f;
#pragma unroll
      for (int g = 0; g < 2; ++g)
#pragma unroll
        for (int r = 0; r < 4; ++r) { p0[g][r] = exp2f(sc0[g][r] - mrun0); sm0 += p0[g][r]; }
      sm0 += __shfl_xor(sm0, 16, 64);
      sm0 += __shfl_xor(sm0, 32, 64);
      lrun0 += sm0;
      u32 pk0[2][2];
#pragma unroll
      for (int g = 0; g < 2; ++g) {
        pk0[g][0] = (u32)f2bf(p0[g][0]) | ((u32)f2bf(p0[g][1]) << 16);
        pk0[g][1] = (u32)f2bf(p0[g][2]) | ((u32)f2bf(p0[g][3]) << 16);
      }
      const u32x4 pw0 = {pk0[0][0], pk0[0][1], pk0[1][0], pk0[1][1]};
      pf0 = __builtin_bit_cast(s16x8, pw0);
    }

    // PV: out^T += V^T * P; each vf read feeds both groups' MFMAs
    __builtin_amdgcn_s_setprio(1);
#pragma unroll
    for (int dd = 0; dd < 8; ++dd) {
      const s16x8 vf = *(const s16x8*)(
          &Vsc[(dd * 16 + l16) * 32 + ((quad ^ ((l16 >> 1) & 3)) << 3)]);
      if (act0)
        acc[0][dd] = __builtin_amdgcn_mfma_f32_16x16x32_bf16(vf, pf0, acc[0][dd], 0, 0, 0);
      acc[1][dd] = __builtin_amdgcn_mfma_f32_16x16x32_bf16(vf, pf1, acc[1][dd], 0, 0, 0);
    }
    __builtin_amdgcn_s_setprio(0);
  }

  // epilogue: per group, lane l16 owns q-row base+l16; dims dd*16+quad*4+r
  const int b = bh >> 4, h = bh & 15;
#pragma unroll
  for (int qg = 0; qg < 2; ++qg) {
    u16* op = out + ((long)b * 2048 + (qg ? qb1 : qb0) + l16) * 2048 + h * 128;
    const float inv_l = 1.0f / (qg ? lrun1 : lrun0);
#pragma unroll
    for (int dd = 0; dd < 8; ++dd) {
      ushort4 o4;
      o4.x = f2bf(acc[qg][dd][0] * inv_l);
      o4.y = f2bf(acc[qg][dd][1] * inv_l);
      o4.z = f2bf(acc[qg][dd][2] * inv_l);
      o4.w = f2bf(acc[qg][dd][3] * inv_l);
      *(ushort4*)(op + dd * 16 + quad * 4) = o4;
    }
  }
}

extern "C" void kernel_launch(void* const* d_in, const int* in_sizes, int n_in,
                              void* d_out, int out_size, void* d_ws, size_t ws_size,
                              hipStream_t stream) {
  const float* hidden = (const float*)d_in[0];  // [2,2048,2048]
  const float* w_qkv = (const float*)d_in[1];   // [6144,2048]
  const float* w_out = (const float*)d_in[2];   // [2048,2048]
  float* out = (float*)d_out;                   // [2,2048,2048] fp32
  char* ws = (char*)d_ws;

  // workspace layout (112 MB total, all 16B aligned)
  u16* hid_b  = (u16*)(ws + (size_t)0);          // hidden bf16
  u16* wqkv_b = (u16*)(ws + (size_t)16777216);   // w_qkv bf16
  u16* wout_b = (u16*)(ws + (size_t)41943040);   // w_out bf16
  u16* qb     = (u16*)(ws + (size_t)50331648);   // q (unroped) [B,H,S,D]
  u16* kb     = (u16*)(ws + (size_t)67108864);   // k (roped)   [B,H,S,D]
  u16* vb     = (u16*)(ws + (size_t)83886080);   // v^T [B,H,D,S]
  u16* ao     = (u16*)(ws + (size_t)100663296);  // attn out [B,S,E]

  cast3_kernel<<<24576, 256, 0, stream>>>(hidden, hid_b, 2097152,
                                          w_qkv, wqkv_b, 3145728,
                                          w_out, wout_b, 1048576);

  // qkv projection, 128^2 R4 GEMM with fused split/transpose/k-rope epilogue
  gemm_bt_kernel<1><<<dim3(48, 32), 256, 0, stream>>>(hid_b, wqkv_b, 2048, 6144,
                                                      nullptr, qb, kb, vb);
  // causal flash attention (q-rope + scale in prologue), 32 q-rows/wave
  attn_kernel<<<512, 256, 0, stream>>>(qb, kb, vb, ao);
  // output projection -> fp32
  gemm_bt_kernel<0><<<dim3(16, 32), 256, 0, stream>>>(ao, wout_b, 2048, 2048,
                                                      out, nullptr, nullptr, nullptr);
}

// Round 6
// 402.087 us; speedup vs baseline: 1.0371x; 1.0371x over previous
//
#include <hip/hip_runtime.h>

typedef unsigned short u16;
typedef unsigned int u32;
typedef __attribute__((ext_vector_type(4))) float f32x4;
typedef __attribute__((ext_vector_type(16))) float f32x16;
typedef __attribute__((ext_vector_type(8))) short s16x8;
typedef __attribute__((ext_vector_type(4))) unsigned int u32x4;

#define DEVI static __device__ __forceinline__

// B=2, S=2048, E=2048, H=16, D=128, MP=4, local=512; qkv cols: [q(512) v(512) k(512)] x4
// k-rope fused into QKV-GEMM epilogue; q-rope (+ (1/sqrt(128))*log2(e) scale) fused into
// attention prologue; softmax in exp2 domain.

#define ROPE_C (-13.287712379549449f / 32.0f)  // -log2(10000)/32
#define QSCALE 0.12751743f                     // log2(e)/sqrt(128)

DEVI u16 f2bf(float f) {
  u32 u = __float_as_uint(f);
  return (u16)((u + 0x7FFFu + ((u >> 16) & 1u)) >> 16);  // round-to-nearest-even
}
DEVI float bf2f(u16 h) { return __uint_as_float(((u32)h) << 16); }

DEVI void async_copy16(const u16* g, u16* l) {
  // dest = wave-uniform LDS base + lane*16 (gfx950 global_load_lds_dwordx4)
  __builtin_amdgcn_global_load_lds((__attribute__((address_space(1))) void*)g,
                                   (__attribute__((address_space(3))) void*)l, 16, 0, 0);
}

// fused fp32->bf16 cast of all three inputs
__global__ __launch_bounds__(256) void cast3_kernel(
    const float* __restrict__ s0, u16* __restrict__ d0, int n0,
    const float* __restrict__ s1, u16* __restrict__ d1, int n1,
    const float* __restrict__ s2, u16* __restrict__ d2, int n2) {
  int i = blockIdx.x * 256 + threadIdx.x;
  const float* s;
  u16* d;
  if (i < n0) {
    s = s0; d = d0;
  } else if (i < n0 + n1) {
    s = s1; d = d1; i -= n0;
  } else if (i < n0 + n1 + n2) {
    s = s2; d = d2; i -= n0 + n1;
  } else {
    return;
  }
  const float4 v = ((const float4*)s)[i];
  ushort4 o;
  o.x = f2bf(v.x); o.y = f2bf(v.y); o.z = f2bf(v.z); o.w = f2bf(v.w);
  ((ushort4*)d)[i] = o;
}

// C[m,n] = sum_k A[m,k]*B[n,k]; A,B row-major bf16, K contiguous (B^T GEMM).
// 128x128 tile, BK=32, 4 waves 2x2 of 64x64, 16x16x32 MFMA, 4x4 frags/wave.
// R4 structure (best measured, 136.5us QKV): A,B staged through 3-deep LDS via
// global_load_lds w16, XOR-swizzled, vmcnt(4) + raw s_barrier in steady state,
// 3 blocks/CU (cross-block overlap hides the barrier drains). Inline epilogue.
// EPI=0: C fp32 store. EPI=1: scatter qkv -> q[B,H,S,D], k(roped)[B,H,S,D], v^T[B,H,D,S].
template <int EPI>
__global__ __launch_bounds__(256, 3) void gemm_bt_kernel(
    const u16* __restrict__ A, const u16* __restrict__ Bm, int K, int N,
    float* __restrict__ C, u16* __restrict__ qo, u16* __restrict__ ko, u16* __restrict__ vo) {
  __shared__ __attribute__((aligned(16))) u16 As[3][128 * 32];  // 8KB each
  __shared__ __attribute__((aligned(16))) u16 Bs[3][128 * 32];  // 8KB each
  const int tid = threadIdx.x;
  const int w = tid >> 6, lane = tid & 63;
  const int quad = lane >> 4, l16 = lane & 15;
  const int wrow = (w >> 1) * 64, wcol = (w & 1) * 64;
  const long tileM = (long)blockIdx.y * 128;
  const long tileN = (long)blockIdx.x * 128;

  f32x4 acc[4][4];
#pragma unroll
  for (int i = 0; i < 4; ++i)
#pragma unroll
    for (int j = 0; j < 4; ++j) acc[i][j] = f32x4{0.f, 0.f, 0.f, 0.f};

  // staging: wave w covers tile rows [w*32, w*32+32) in two 16-row chunks.
  const u16* aptr[2];
  const u16* bptr[2];
  int ldso[2];
#pragma unroll
  for (int c = 0; c < 2; ++c) {
    const int r0 = (w * 2 + c) * 16;
    const int row = r0 + (lane >> 2);
    const int colsw = (((lane & 3) ^ ((row >> 1) & 3)) << 3);
    aptr[c] = A + (tileM + row) * (long)K + colsw;
    bptr[c] = Bm + (tileN + row) * (long)K + colsw;
    ldso[c] = r0 * 32;
  }

  auto stage = [&](int k0, int buf) {
#pragma unroll
    for (int c = 0; c < 2; ++c) {
      async_copy16(aptr[c] + k0, &As[buf][ldso[c]]);
      async_copy16(bptr[c] + k0, &Bs[buf][ldso[c]]);
    }
  };

  stage(0, 0);
  stage(32, 1);

  const int psw = (quad ^ ((l16 >> 1) & 3)) << 3;  // read-side swizzle (lane-constant)

  int bt = 0;
  for (int k0 = 0; k0 < K; k0 += 32) {
    if (k0 + 32 < K)
      __builtin_amdgcn_s_waitcnt(0x0f74);  // vmcnt(4): tile t landed, t+1 in flight
    else
      __builtin_amdgcn_s_waitcnt(0x0f70);  // last tile: vmcnt(0)
    __builtin_amdgcn_s_barrier();          // raw barrier: no compiler-forced drain
    if (k0 + 64 < K) stage(k0 + 64, bt == 0 ? 2 : bt - 1);

    s16x8 af[4], bfr[4];
#pragma unroll
    for (int i = 0; i < 4; ++i)
      af[i] = *(const s16x8*)(&As[bt][(wrow + i * 16 + l16) * 32 + psw]);
#pragma unroll
    for (int j = 0; j < 4; ++j)
      bfr[j] = *(const s16x8*)(&Bs[bt][(wcol + j * 16 + l16) * 32 + psw]);
#pragma unroll
    for (int i = 0; i < 4; ++i)
#pragma unroll
      for (int j = 0; j < 4; ++j)
        acc[i][j] = __builtin_amdgcn_mfma_f32_16x16x32_bf16(af[i], bfr[j], acc[i][j], 0, 0, 0);
    bt = bt == 2 ? 0 : bt + 1;
  }

  // ---- inline epilogue (single call site; acc stays in registers) ----
  const int b = (int)(tileM >> 11);  // 128-row tile never straddles batch
#pragma unroll
  for (int i = 0; i < 4; ++i) {
#pragma unroll
    for (int j = 0; j < 4; ++j) {
      const int rowb = (int)((tileM + wrow + i * 16 + quad * 4) & 2047);  // s of reg 0
      if (EPI == 0) {
#pragma unroll
        for (int r = 0; r < 4; ++r) {
          const long row = tileM + wrow + i * 16 + quad * 4 + r;
          C[row * N + tileN + wcol + j * 16 + l16] = acc[i][j][r];
        }
      } else {
        const long col0 = tileN + wcol + j * 16;  // wave-uniform base col of this frag
        const int mp = (int)(col0 / 1536);
        const int cc0 = (int)(col0 - (long)mp * 1536);
        const int part = cc0 >> 9;     // 0:q 1:v 2:k (uniform per frag)
        const int idx0 = cc0 & 511;
        const int head = mp * 4 + (idx0 >> 7);
        const int dim0 = idx0 & 127;
        const int dim = dim0 + l16;
        const long bh = (long)(b * 16 + head);
        if (part == 1) {
#pragma unroll
          for (int r = 0; r < 4; ++r)
            vo[(bh * 128 + dim) * 2048 + rowb + r] = f2bf(acc[i][j][r]);  // v^T
        } else {
          float y[4];
          if (part == 2 && dim0 < 64) {
            // k-rope: pair partner is adjacent lane (col parity == l16 parity)
            const int jj = dim >> 1;
            const float inv = exp2f((float)jj * ROPE_C);
#pragma unroll
            for (int r = 0; r < 4; ++r) {
              const float v = acc[i][j][r];
              const float pv = __shfl_xor(v, 1, 64);
              const float ang = (float)(rowb + r) * inv;
              const float sn = __sinf(ang), cs = __cosf(ang);
              y[r] = (l16 & 1) ? (v * cs + pv * sn) : (v * cs - pv * sn);
            }
          } else {
#pragma unroll
            for (int r = 0; r < 4; ++r) y[r] = acc[i][j][r];
          }
          u16* dst = (part == 0) ? qo : ko;
#pragma unroll
          for (int r = 0; r < 4; ++r)
            dst[(bh * 2048 + rowb + r) * 128 + dim] = f2bf(y[r]);
        }
      }
    }
  }
}

// Flash attention v6: 32x32 MFMA, 32 q-rows per wave. Block = 128 threads (2 waves,
// 64 q-rows) -> grid 1024, SAME heavy-first mapping as the proven v4.3. 2-deep LDS
// ring (32KB) -> 4 blocks/CU, 8 waves/CU, VGPR cap 256.
// Per 32-key tile per wave: QK^T = 8 ds_read_b128 + 8 mfma_32x32x16; PV = 8 + 8 --
// 16 reads per 32 q-rows vs v4.3's 16 per 16 q-rows (LDS cost/q-row halves; K/V DMA
// per q-row halves; MFMA issue cyc/row 4 vs 5).
// S^T = K*Q^T (A=K, B=Q). C layout (verified m74/m101): col=lane&31=q-row,
// row=(reg&3)+8*(reg>>2)+4*(lane>>5). Zero-shuffle P: K rows staged via block-swap
// involution s (swap low-2 bits of 4-row-block index) so C regs [8ki..8ki+7] ARE the
// PV B-frag for keys 16ki+8h (verified per (ki,h,j)). Softmax: 15 in-lane fmax +
// 1 shfl_xor(32); m/l per lane (2 lanes per q-row hold identical m/l).
// QK^T uses 2 interleaved accumulator chains (even/odd dim-instr) merged at the end
// (avoids an 8-deep dependent MFMA chain; fp-add reorder, sub-ulp).
// Keeps: setprio (T5), defer-max THR=8 (T13), granule-XOR staging, wait-then-barrier
// ring discipline (vmcnt(0) before barrier; stage(t+1) after barrier into buf (t-1)&1).
__global__ __launch_bounds__(128, 2) void attn_kernel(
    const u16* __restrict__ q, const u16* __restrict__ k,
    const u16* __restrict__ vT, u16* __restrict__ out) {
  __shared__ __attribute__((aligned(16))) u16 Ks[2][32 * 128];  // 8KB each
  __shared__ __attribute__((aligned(16))) u16 Vs[2][128 * 32];  // 8KB each
  const int tid = threadIdx.x;
  const int w = tid >> 6, lane = tid & 63;
  const int l32 = lane & 31, h = lane >> 5;
  const int qt = 31 - (blockIdx.x >> 5);  // heavy tiles dispatched first
  const int bh = blockIdx.x & 31;
  const int qb = qt * 64 + w * 32;  // wave's 32 q-rows: [qb, qb+32)

  const u16* qp = q + ((long)bh * 2048 + qb) * 128;
  const u16* kp = k + (long)bh * 2048 * 128;
  const u16* vp = vT + (long)bh * 128 * 2048;

  // Q B-frag: Q[n = l32][k-dim = c*16 + h*8 + j], roped + scaled in fp32
  const float spos = (float)(qb + l32);
  s16x8 qf[8];
#pragma unroll
  for (int c = 0; c < 8; ++c) {
    const s16x8 raw = *(const s16x8*)(qp + l32 * 128 + c * 16 + h * 8);
    s16x8 ov;
    if (c < 4) {  // dims < 64: rotate pairs (in-lane: 2m, 2m+1)
#pragma unroll
      for (int m = 0; m < 4; ++m) {
        const int jj = c * 8 + h * 4 + m;  // dim/2
        const float inv = exp2f((float)jj * ROPE_C);
        const float ang = spos * inv;
        const float sn = __sinf(ang), cs = __cosf(ang);
        const float x0 = bf2f((u16)raw[2 * m]), x1 = bf2f((u16)raw[2 * m + 1]);
        ov[2 * m] = (short)f2bf((x0 * cs - x1 * sn) * QSCALE);
        ov[2 * m + 1] = (short)f2bf((x1 * cs + x0 * sn) * QSCALE);
      }
    } else {  // dims >= 64: pass-through, scale only
#pragma unroll
      for (int e = 0; e < 8; ++e) ov[e] = (short)f2bf(bf2f((u16)raw[e]) * QSCALE);
    }
    qf[c] = ov;
  }

  f32x16 acc[4];  // out^T: acc[dt] dim = dt*32 + (r&3)+8*(r>>2)+4h, col = q-row l32
#pragma unroll
  for (int dt = 0; dt < 4; ++dt)
#pragma unroll
    for (int r = 0; r < 16; ++r) acc[dt][r] = 0.f;
  float mrun = -1e30f, lrun = 0.f;  // per-lane (q-row l32; both halves identical)

  // stage one 32-key tile: 8 DMAs/wave (4 K + 4 V). K rows PERMUTED by the
  // block-swap involution s: LDS row rr holds global key s(rr) where
  // s: block b=rr>>2 -> (b&4)|((b&1)<<1)|((b>>1)&1), within-block offset kept.
  auto stage = [&](int k0, int buf) {
    const int cl = lane & 15;
#pragma unroll
    for (int i = 0; i < 4; ++i) {
      const int r0 = 4 * (4 * w + i);     // 4 LDS rows per DMA
      const int rr = r0 + (lane >> 4);    // LDS row this lane fills
      const int bb = rr >> 2;
      const int bs = (bb & 4) | ((bb & 1) << 1) | ((bb >> 1) & 1);
      const int sk = bs * 4 + (rr & 3);   // global key stored at row rr
      async_copy16(kp + (long)(k0 + sk) * 128 + ((cl ^ (rr & 15)) << 3),
                   &Ks[buf][r0 * 128]);
    }
#pragma unroll
    for (int i = 0; i < 4; ++i) {
      const int d0 = 16 * (4 * w + i);    // 16 V dim-rows per DMA
      const int d = d0 + (lane >> 2);
      const int c4 = lane & 3;
      async_copy16(vp + (long)d * 2048 + k0 + ((c4 ^ ((d >> 1) & 3)) << 3),
                   &Vs[buf][d0 * 32]);
    }
  };

  const int nt = 2 * qt + 2;  // block covers keys [0, 64*qt+64)
  stage(0, 0);

  for (int t = 0; t < nt; ++t) {
    const int k0 = t * 32;
    __builtin_amdgcn_s_waitcnt(0x0f70);  // vmcnt(0): my tile-t DMAs landed
    __builtin_amdgcn_s_barrier();        // all waves' landed; buf (t+1)&1 free
    if (t + 1 < nt) stage(k0 + 32, (t + 1) & 1);
    const u16* Ksc = Ks[t & 1];
    const u16* Vsc = Vs[t & 1];
    if (k0 > qb + 31) continue;  // wave fully masked (last tile, wave 0 only)

    // S^T = K*Q^T: A-frag lane l: m=l32 (LDS row, holds key s(l32)), k=h*8+j.
    // Two interleaved chains (even/odd c) -> dependency distance 2.
    f32x16 sa, sb;
#pragma unroll
    for (int r = 0; r < 16; ++r) { sa[r] = 0.f; sb[r] = 0.f; }
    __builtin_amdgcn_s_setprio(1);
#pragma unroll
    for (int c = 0; c < 8; c += 2) {
      const s16x8 kf0 = *(const s16x8*)(
          &Ksc[l32 * 128 + ((((c << 1) + h) ^ (l32 & 15)) << 3)]);
      const s16x8 kf1 = *(const s16x8*)(
          &Ksc[l32 * 128 + (((((c + 1) << 1) + h) ^ (l32 & 15)) << 3)]);
      sa = __builtin_amdgcn_mfma_f32_32x32x16_bf16(kf0, qf[c], sa, 0, 0, 0);
      sb = __builtin_amdgcn_mfma_f32_32x32x16_bf16(kf1, qf[c + 1], sb, 0, 0, 0);
    }
    __builtin_amdgcn_s_setprio(0);
    f32x16 sc;
#pragma unroll
    for (int r = 0; r < 16; ++r) sc[r] = sa[r] + sb[r];

    if (k0 + 31 > qb) {  // tile crosses the diagonal (wave-uniform branch)
      const int qrow = qb + l32;
#pragma unroll
      for (int r = 0; r < 16; ++r) {
        const int rr = (r & 3) + ((r >> 2) << 3) + 4 * h;  // C row index
        const int bb = rr >> 2;
        const int bs = (bb & 4) | ((bb & 1) << 1) | ((bb >> 1) & 1);
        const int key = k0 + bs * 4 + (rr & 3);  // global key of this reg
        if (key > qrow) sc[r] = -1e30f;
      }
    }
    // online softmax (exp2 domain), defer-max (T13)
    float mx = sc[0];
#pragma unroll
    for (int r = 1; r < 16; ++r) mx = fmaxf(mx, sc[r]);
    mx = fmaxf(mx, __shfl_xor(mx, 32, 64));
    if (__any(mx > mrun + 8.f)) {  // wave-uniform rescale
      const float mnew = fmaxf(mrun, mx);
      const float alpha = exp2f(mrun - mnew);
      mrun = mnew;
      lrun *= alpha;
#pragma unroll
      for (int dt = 0; dt < 4; ++dt)
#pragma unroll
        for (int r = 0; r < 16; ++r) acc[dt][r] *= alpha;
    }
    float p[16];
    float sm = 0.f;
#pragma unroll
    for (int r = 0; r < 16; ++r) { p[r] = exp2f(sc[r] - mrun); sm += p[r]; }
    sm += __shfl_xor(sm, 32, 64);
    lrun += sm;

    // P -> PV B-frag, fully in-lane: pf_ki elem j = C reg 8ki+j (block-swap staging)
    u32 pw[8];
#pragma unroll
    for (int x = 0; x < 8; ++x)
      pw[x] = (u32)f2bf(p[2 * x]) | ((u32)f2bf(p[2 * x + 1]) << 16);
    const u32x4 pwa = {pw[0], pw[1], pw[2], pw[3]};
    const u32x4 pwb = {pw[4], pw[5], pw[6], pw[7]};
    const s16x8 pf0 = __builtin_bit_cast(s16x8, pwa);
    const s16x8 pf1 = __builtin_bit_cast(s16x8, pwb);

    // PV: out^T += V^T * P (A = V^T[m=dim l32][k=key 16ki+8h+j], B = P)
    __builtin_amdgcn_s_setprio(1);
#pragma unroll
    for (int ki = 0; ki < 2; ++ki) {
      const s16x8 pf = ki ? pf1 : pf0;
#pragma unroll
      for (int dt = 0; dt < 4; ++dt) {
        const int d0 = dt * 32 + l32;
        const s16x8 vf = *(const s16x8*)(
            &Vsc[d0 * 32 + ((((ki << 1) + h) ^ ((l32 >> 1) & 3)) << 3)]);
        acc[dt] = __builtin_amdgcn_mfma_f32_32x32x16_bf16(vf, pf, acc[dt], 0, 0, 0);
      }
    }
    __builtin_amdgcn_s_setprio(0);
  }

  // epilogue: lane pair (l32, +32) owns q-row qb+l32; dims dt*32 + G*8 + 4h + 0..3
  const int b = bh >> 4, hh = bh & 15;
  u16* op = out + ((long)b * 2048 + qb + l32) * 2048 + hh * 128;
  const float inv_l = 1.0f / lrun;
#pragma unroll
  for (int dt = 0; dt < 4; ++dt) {
#pragma unroll
    for (int G = 0; G < 4; ++G) {
      ushort4 o4;
      o4.x = f2bf(acc[dt][G * 4 + 0] * inv_l);
      o4.y = f2bf(acc[dt][G * 4 + 1] * inv_l);
      o4.z = f2bf(acc[dt][G * 4 + 2] * inv_l);
      o4.w = f2bf(acc[dt][G * 4 + 3] * inv_l);
      *(ushort4*)(op + dt * 32 + G * 8 + 4 * h) = o4;
    }
  }
}

extern "C" void kernel_launch(void* const* d_in, const int* in_sizes, int n_in,
                              void* d_out, int out_size, void* d_ws, size_t ws_size,
                              hipStream_t stream) {
  const float* hidden = (const float*)d_in[0];  // [2,2048,2048]
  const float* w_qkv = (const float*)d_in[1];   // [6144,2048]
  const float* w_out = (const float*)d_in[2];   // [2048,2048]
  float* out = (float*)d_out;                   // [2,2048,2048] fp32
  char* ws = (char*)d_ws;

  // workspace layout (112 MB total, all 16B aligned)
  u16* hid_b  = (u16*)(ws + (size_t)0);          // hidden bf16
  u16* wqkv_b = (u16*)(ws + (size_t)16777216);   // w_qkv bf16
  u16* wout_b = (u16*)(ws + (size_t)41943040);   // w_out bf16
  u16* qb     = (u16*)(ws + (size_t)50331648);   // q (unroped) [B,H,S,D]
  u16* kb     = (u16*)(ws + (size_t)67108864);   // k (roped)   [B,H,S,D]
  u16* vb     = (u16*)(ws + (size_t)83886080);   // v^T [B,H,D,S]
  u16* ao     = (u16*)(ws + (size_t)100663296);  // attn out [B,S,E]

  cast3_kernel<<<24576, 256, 0, stream>>>(hidden, hid_b, 2097152,
                                          w_qkv, wqkv_b, 3145728,
                                          w_out, wout_b, 1048576);

  // qkv projection, 128^2 R4 GEMM with fused split/transpose/k-rope epilogue
  gemm_bt_kernel<1><<<dim3(48, 32), 256, 0, stream>>>(hid_b, wqkv_b, 2048, 6144,
                                                      nullptr, qb, kb, vb);
  // causal flash attention (q-rope + scale in prologue), 32x32 MFMA, 32 q-rows/wave
  attn_kernel<<<1024, 128, 0, stream>>>(qb, kb, vb, ao);
  // output projection -> fp32
  gemm_bt_kernel<0><<<dim3(16, 32), 256, 0, stream>>>(ao, wout_b, 2048, 2048,
                                                      out, nullptr, nullptr, nullptr);
}

// Round 7
// 381.242 us; speedup vs baseline: 1.0938x; 1.0547x over previous
//
#include <hip/hip_runtime.h>

typedef unsigned short u16;
typedef unsigned int u32;
typedef __attribute__((ext_vector_type(4))) float f32x4;
typedef __attribute__((ext_vector_type(8))) short s16x8;
typedef __attribute__((ext_vector_type(4))) unsigned int u32x4;

#define DEVI static __device__ __forceinline__

// B=2, S=2048, E=2048, H=16, D=128, MP=4, local=512; qkv cols: [q(512) v(512) k(512)] x4
// k-rope fused into QKV-GEMM epilogue; q-rope (+ (1/sqrt(128))*log2(e) scale) fused into
// attention prologue; softmax in exp2 domain.

#define ROPE_C (-13.287712379549449f / 32.0f)  // -log2(10000)/32
#define QSCALE 0.12751743f                     // log2(e)/sqrt(128)

DEVI u16 f2bf(float f) {
  u32 u = __float_as_uint(f);
  return (u16)((u + 0x7FFFu + ((u >> 16) & 1u)) >> 16);  // round-to-nearest-even
}
DEVI float bf2f(u16 h) { return __uint_as_float(((u32)h) << 16); }

// HW packed fp32->bf16 RNE: 1 instr replaces ~10 VALU ops of 2x f2bf (+pack).
// Rounding identical to f2bf (both RNE) -> bit-identical outputs.
DEVI u32 cvtpk_bf16(float lo, float hi) {
  u32 r;
  asm("v_cvt_pk_bf16_f32 %0, %1, %2" : "=v"(r) : "v"(lo), "v"(hi));
  return r;
}

DEVI void async_copy16(const u16* g, u16* l) {
  // dest = wave-uniform LDS base + lane*16 (gfx950 global_load_lds_dwordx4)
  __builtin_amdgcn_global_load_lds((__attribute__((address_space(1))) void*)g,
                                   (__attribute__((address_space(3))) void*)l, 16, 0, 0);
}

// fused fp32->bf16 cast of all three inputs
__global__ __launch_bounds__(256) void cast3_kernel(
    const float* __restrict__ s0, u16* __restrict__ d0, int n0,
    const float* __restrict__ s1, u16* __restrict__ d1, int n1,
    const float* __restrict__ s2, u16* __restrict__ d2, int n2) {
  int i = blockIdx.x * 256 + threadIdx.x;
  const float* s;
  u16* d;
  if (i < n0) {
    s = s0; d = d0;
  } else if (i < n0 + n1) {
    s = s1; d = d1; i -= n0;
  } else if (i < n0 + n1 + n2) {
    s = s2; d = d2; i -= n0 + n1;
  } else {
    return;
  }
  const float4 v = ((const float4*)s)[i];
  ushort4 o;
  o.x = f2bf(v.x); o.y = f2bf(v.y); o.z = f2bf(v.z); o.w = f2bf(v.w);
  ((ushort4*)d)[i] = o;
}

// C[m,n] = sum_k A[m,k]*B[n,k]; A,B row-major bf16, K contiguous (B^T GEMM).
// 128x128 tile, BK=32, 4 waves 2x2 of 64x64, 16x16x32 MFMA, 4x4 frags/wave.
// R4 structure (best measured, 136.5us QKV): A,B staged through 3-deep LDS via
// global_load_lds w16, XOR-swizzled, vmcnt(4) + raw s_barrier in steady state,
// 3 blocks/CU (cross-block overlap hides the barrier drains). Inline epilogue.
// EPI=0: C fp32 store. EPI=1: scatter qkv -> q[B,H,S,D], k(roped)[B,H,S,D], v^T[B,H,D,S].
template <int EPI>
__global__ __launch_bounds__(256, 3) void gemm_bt_kernel(
    const u16* __restrict__ A, const u16* __restrict__ Bm, int K, int N,
    float* __restrict__ C, u16* __restrict__ qo, u16* __restrict__ ko, u16* __restrict__ vo) {
  __shared__ __attribute__((aligned(16))) u16 As[3][128 * 32];  // 8KB each
  __shared__ __attribute__((aligned(16))) u16 Bs[3][128 * 32];  // 8KB each
  const int tid = threadIdx.x;
  const int w = tid >> 6, lane = tid & 63;
  const int quad = lane >> 4, l16 = lane & 15;
  const int wrow = (w >> 1) * 64, wcol = (w & 1) * 64;
  const long tileM = (long)blockIdx.y * 128;
  const long tileN = (long)blockIdx.x * 128;

  f32x4 acc[4][4];
#pragma unroll
  for (int i = 0; i < 4; ++i)
#pragma unroll
    for (int j = 0; j < 4; ++j) acc[i][j] = f32x4{0.f, 0.f, 0.f, 0.f};

  // staging: wave w covers tile rows [w*32, w*32+32) in two 16-row chunks.
  const u16* aptr[2];
  const u16* bptr[2];
  int ldso[2];
#pragma unroll
  for (int c = 0; c < 2; ++c) {
    const int r0 = (w * 2 + c) * 16;
    const int row = r0 + (lane >> 2);
    const int colsw = (((lane & 3) ^ ((row >> 1) & 3)) << 3);
    aptr[c] = A + (tileM + row) * (long)K + colsw;
    bptr[c] = Bm + (tileN + row) * (long)K + colsw;
    ldso[c] = r0 * 32;
  }

  auto stage = [&](int k0, int buf) {
#pragma unroll
    for (int c = 0; c < 2; ++c) {
      async_copy16(aptr[c] + k0, &As[buf][ldso[c]]);
      async_copy16(bptr[c] + k0, &Bs[buf][ldso[c]]);
    }
  };

  stage(0, 0);
  stage(32, 1);

  const int psw = (quad ^ ((l16 >> 1) & 3)) << 3;  // read-side swizzle (lane-constant)

  int bt = 0;
  for (int k0 = 0; k0 < K; k0 += 32) {
    if (k0 + 32 < K)
      __builtin_amdgcn_s_waitcnt(0x0f74);  // vmcnt(4): tile t landed, t+1 in flight
    else
      __builtin_amdgcn_s_waitcnt(0x0f70);  // last tile: vmcnt(0)
    __builtin_amdgcn_s_barrier();          // raw barrier: no compiler-forced drain
    if (k0 + 64 < K) stage(k0 + 64, bt == 0 ? 2 : bt - 1);

    s16x8 af[4], bfr[4];
#pragma unroll
    for (int i = 0; i < 4; ++i)
      af[i] = *(const s16x8*)(&As[bt][(wrow + i * 16 + l16) * 32 + psw]);
#pragma unroll
    for (int j = 0; j < 4; ++j)
      bfr[j] = *(const s16x8*)(&Bs[bt][(wcol + j * 16 + l16) * 32 + psw]);
#pragma unroll
    for (int i = 0; i < 4; ++i)
#pragma unroll
      for (int j = 0; j < 4; ++j)
        acc[i][j] = __builtin_amdgcn_mfma_f32_16x16x32_bf16(af[i], bfr[j], acc[i][j], 0, 0, 0);
    bt = bt == 2 ? 0 : bt + 1;
  }

  // ---- inline epilogue (single call site; acc stays in registers) ----
  const int b = (int)(tileM >> 11);  // 128-row tile never straddles batch
#pragma unroll
  for (int i = 0; i < 4; ++i) {
#pragma unroll
    for (int j = 0; j < 4; ++j) {
      const int rowb = (int)((tileM + wrow + i * 16 + quad * 4) & 2047);  // s of reg 0
      if (EPI == 0) {
#pragma unroll
        for (int r = 0; r < 4; ++r) {
          const long row = tileM + wrow + i * 16 + quad * 4 + r;
          C[row * N + tileN + wcol + j * 16 + l16] = acc[i][j][r];
        }
      } else {
        const long col0 = tileN + wcol + j * 16;  // wave-uniform base col of this frag
        const int mp = (int)(col0 / 1536);
        const int cc0 = (int)(col0 - (long)mp * 1536);
        const int part = cc0 >> 9;     // 0:q 1:v 2:k (uniform per frag)
        const int idx0 = cc0 & 511;
        const int head = mp * 4 + (idx0 >> 7);
        const int dim0 = idx0 & 127;
        const int dim = dim0 + l16;
        const long bh = (long)(b * 16 + head);
        if (part == 1) {
          // v^T: r-consecutive addresses -> 2 cvt_pk + one 8B store (was 4 f2bf + 4 stores)
          uint2 o2;
          o2.x = cvtpk_bf16(acc[i][j][0], acc[i][j][1]);
          o2.y = cvtpk_bf16(acc[i][j][2], acc[i][j][3]);
          *(uint2*)(vo + (bh * 128 + dim) * 2048 + rowb) = o2;
        } else {
          float y[4];
          if (part == 2 && dim0 < 64) {
            // k-rope: pair partner is adjacent lane (col parity == l16 parity)
            const int jj = dim >> 1;
            const float inv = exp2f((float)jj * ROPE_C);
#pragma unroll
            for (int r = 0; r < 4; ++r) {
              const float v = acc[i][j][r];
              const float pv = __shfl_xor(v, 1, 64);
              const float ang = (float)(rowb + r) * inv;
              const float sn = __sinf(ang), cs = __cosf(ang);
              y[r] = (l16 & 1) ? (v * cs + pv * sn) : (v * cs - pv * sn);
            }
          } else {
#pragma unroll
            for (int r = 0; r < 4; ++r) y[r] = acc[i][j][r];
          }
          u16* dst = (part == 0) ? qo : ko;
#pragma unroll
          for (int r = 0; r < 4; ++r)
            dst[(bh * 2048 + rowb + r) * 128 + dim] = f2bf(y[r]);
        }
      }
    }
  }
}

// Flash attention v4.4 (= proven v4.3 structure + cvt_pk packing). Block = 64 q rows
// (4 waves x 16 rows), 32-key tiles, 3-deep LDS ring + counted vmcnt(4) (4 DMAs/wave
// /tile). S^T = K*Q^T (A=K, B=Q): each lane holds 8 scores of ONE q-row -> softmax
// reduce = in-lane + 2 shfl; m/l scalars per lane.
// Zero-shuffle P: K staged in PERMUTED row order (LDS row rr holds key
// ((rr>>2)&3)*8+((rr>>4)&1)*4+(rr&3)) so the S^T C-layout IS the PV B-frag layout.
// v4.4: all bf16 packing on hot paths via v_cvt_pk_bf16_f32 (P-pack per tile: ~36
// VALU -> 4 instr; prologue + epilogue one-shot). Rounding identical to f2bf.
// Keeps: setprio (T5), defer-max THR=8 (T13), QK^T g-interleave, raw s_barrier after
// explicit vmcnt. PV = V^T*P gives out^T; 8B stores. Heavy-first grid, 3 blocks/CU.
__global__ __launch_bounds__(256, 3) void attn_kernel(
    const u16* __restrict__ q, const u16* __restrict__ k,
    const u16* __restrict__ vT, u16* __restrict__ out) {
  __shared__ __attribute__((aligned(16))) u16 Ks[3][32 * 128];  // 8KB each
  __shared__ __attribute__((aligned(16))) u16 Vs[3][128 * 32];  // 8KB each
  const int tid = threadIdx.x;
  const int w = tid >> 6, lane = tid & 63;
  const int quad = lane >> 4, l16 = lane & 15;
  const int qt = 31 - (blockIdx.x >> 5);  // heavy tiles dispatched first
  const int bh = blockIdx.x & 31;
  const int qbase = qt * 64 + w * 16;

  const u16* qp = q + ((long)bh * 2048 + qbase) * 128;
  const u16* kp = k + (long)bh * 2048 * 128;
  const u16* vp = vT + (long)bh * 128 * 2048;

  // Q B-frag: Q[n=l16][kdim = c*32 + quad*8 + j], roped + scaled in fp32
  const float spos = (float)(qbase + l16);
  s16x8 qf[4];
#pragma unroll
  for (int c = 0; c < 4; ++c) {
    const s16x8 raw = *(const s16x8*)(qp + l16 * 128 + c * 32 + quad * 8);
    u32 pw4[4];
    if (c < 2) {  // dims < 64: rotate pairs (in-lane: 2m, 2m+1)
#pragma unroll
      for (int m = 0; m < 4; ++m) {
        const int jj = c * 16 + quad * 4 + m;
        const float inv = exp2f((float)jj * ROPE_C);
        const float ang = spos * inv;
        const float sn = __sinf(ang), cs = __cosf(ang);
        const float x0 = bf2f((u16)raw[2 * m]), x1 = bf2f((u16)raw[2 * m + 1]);
        pw4[m] = cvtpk_bf16((x0 * cs - x1 * sn) * QSCALE, (x1 * cs + x0 * sn) * QSCALE);
      }
    } else {      // dims >= 64: pass-through, scale only
#pragma unroll
      for (int m = 0; m < 4; ++m)
        pw4[m] = cvtpk_bf16(bf2f((u16)raw[2 * m]) * QSCALE,
                            bf2f((u16)raw[2 * m + 1]) * QSCALE);
    }
    const u32x4 pv4 = {pw4[0], pw4[1], pw4[2], pw4[3]};
    qf[c] = __builtin_bit_cast(s16x8, pv4);
  }

  f32x4 acc[8];  // out^T: acc[dd] rows = dims dd*16+quad*4+r, col = q-row l16
#pragma unroll
  for (int d = 0; d < 8; ++d) acc[d] = f32x4{0.f, 0.f, 0.f, 0.f};
  float mrun = -1e30f, lrun = 0.f;  // per-lane scalars (q-row = qbase+l16)

  // stage one 32-key tile: wave w stages LDS K-rows [w*8,w*8+8) and V dims
  // [w*32,w*32+32); exactly 4 async DMAs per wave per tile (vmcnt is per-wave).
  // K rows PERMUTED: LDS row rr holds global key ((rr>>2)&3)*8+((rr>>4)&1)*4+(rr&3).
  auto stage = [&](int k0, int buf) {
    const int ko = lane >> 4, cl = lane & 15;
#pragma unroll
    for (int i = 0; i < 2; ++i) {
      const int keyt = w * 8 + i * 4;
      const int rr = keyt + ko;  // LDS row this lane fills
      const int sk = ((rr >> 2) & 3) * 8 + ((rr >> 4) & 1) * 4 + (rr & 3);
      async_copy16(kp + (long)(k0 + sk) * 128 + ((cl ^ (rr & 15)) << 3),
                   &Ks[buf][keyt * 128]);
    }
    const int ld = lane >> 2, c4 = lane & 3;
#pragma unroll
    for (int i = 0; i < 2; ++i) {
      const int db = w * 32 + i * 16;
      const int d = db + ld;
      async_copy16(vp + (long)d * 2048 + k0 + ((c4 ^ ((d >> 1) & 3)) << 3),
                   &Vs[buf][db * 32]);
    }
  };

  const int nt = 2 * qt + 2;  // nt >= 2 always
  stage(0, 0);
  stage(32, 1);

  int bt = 0;
  for (int t = 0; t < nt; ++t) {
    const int k0 = t * 32;
    if (t + 1 < nt)
      __builtin_amdgcn_s_waitcnt(0x0f74);  // vmcnt(4): tile t landed, t+1 in flight
    else
      __builtin_amdgcn_s_waitcnt(0x0f70);  // last tile: vmcnt(0)
    __builtin_amdgcn_s_barrier();          // all waves' tile-t DMA done; buf t-1 free
    if (t + 2 < nt) stage(k0 + 64, bt == 0 ? 2 : bt - 1);
    const u16* Ksc = Ks[bt];
    const u16* Vsc = Vs[bt];

    // S^T = K*Q^T: sc[g] reg r at lane-quad u holds key k0 + u*8 + g*4 + r (permuted
    // staging), col = q-row l16. g interleaved inside c: consecutive MFMAs independent.
    f32x4 sc[2];
    sc[0] = f32x4{0.f, 0.f, 0.f, 0.f};
    sc[1] = f32x4{0.f, 0.f, 0.f, 0.f};
    __builtin_amdgcn_s_setprio(1);
#pragma unroll
    for (int c = 0; c < 4; ++c) {
      const s16x8 kf0 = *(const s16x8*)(
          &Ksc[(0 * 16 + l16) * 128 + ((((c << 2) + quad) ^ l16) << 3)]);
      const s16x8 kf1 = *(const s16x8*)(
          &Ksc[(1 * 16 + l16) * 128 + ((((c << 2) + quad) ^ l16) << 3)]);
      sc[0] = __builtin_amdgcn_mfma_f32_16x16x32_bf16(kf0, qf[c], sc[0], 0, 0, 0);
      sc[1] = __builtin_amdgcn_mfma_f32_16x16x32_bf16(kf1, qf[c], sc[1], 0, 0, 0);
    }
    __builtin_amdgcn_s_setprio(0);
    if (k0 + 31 > qbase) {  // tile may cross the diagonal (wave-uniform branch)
      const int qrow = qbase + l16;
#pragma unroll
      for (int g = 0; g < 2; ++g) {
        const int keyb = k0 + quad * 8 + g * 4;  // permuted key id of reg 0
#pragma unroll
        for (int r = 0; r < 4; ++r)
          if (keyb + r > qrow) sc[g][r] = -1e30f;
      }
    }
    // online softmax (exp2 domain), defer-max (T13): skip the O(acc) rescale while
    // the tile max stays within THR=8 of the running max (P bounded by 2^8).
    float mx = fmaxf(fmaxf(fmaxf(sc[0][0], sc[0][1]), fmaxf(sc[0][2], sc[0][3])),
                     fmaxf(fmaxf(sc[1][0], sc[1][1]), fmaxf(sc[1][2], sc[1][3])));
    mx = fmaxf(mx, __shfl_xor(mx, 16, 64));
    mx = fmaxf(mx, __shfl_xor(mx, 32, 64));
    if (__any(mx > mrun + 8.f)) {  // wave-uniform rescale
      const float mnew = fmaxf(mrun, mx);
      const float alpha = exp2f(mrun - mnew);
      mrun = mnew;
      lrun *= alpha;
#pragma unroll
      for (int d = 0; d < 8; ++d)
#pragma unroll
        for (int r = 0; r < 4; ++r) acc[d][r] *= alpha;
    }
    float p[2][4];
    float sm = 0.f;
#pragma unroll
    for (int g = 0; g < 2; ++g)
#pragma unroll
      for (int r = 0; r < 4; ++r) { p[g][r] = exp2f(sc[g][r] - mrun); sm += p[g][r]; }
    sm += __shfl_xor(sm, 16, 64);
    sm += __shfl_xor(sm, 32, 64);
    lrun += sm;

    // P -> PV B-frag, fully in-lane (permuted staging made C-layout == B-frag layout);
    // HW cvt_pk: 4 instr for the whole pack (was ~36 VALU of f2bf+or).
    const u32x4 pw = {cvtpk_bf16(p[0][0], p[0][1]), cvtpk_bf16(p[0][2], p[0][3]),
                      cvtpk_bf16(p[1][0], p[1][1]), cvtpk_bf16(p[1][2], p[1][3])};
    const s16x8 pf = __builtin_bit_cast(s16x8, pw);

    // PV: out^T += V^T * P  (A = V^T[m=dim][k=key], B = P[n=qrow][k=key])
    __builtin_amdgcn_s_setprio(1);
#pragma unroll
    for (int dd = 0; dd < 8; ++dd) {
      const s16x8 vf = *(const s16x8*)(
          &Vsc[(dd * 16 + l16) * 32 + ((quad ^ ((l16 >> 1) & 3)) << 3)]);
      acc[dd] = __builtin_amdgcn_mfma_f32_16x16x32_bf16(vf, pf, acc[dd], 0, 0, 0);
    }
    __builtin_amdgcn_s_setprio(0);
    bt = bt == 2 ? 0 : bt + 1;
  }

  // epilogue: lane l16 owns q-row qbase+l16; dims dd*16+quad*4+r -> 8B stores
  const int b = bh >> 4, h = bh & 15;
  u16* op = out + ((long)b * 2048 + qbase + l16) * 2048 + h * 128;
  const float inv_l = 1.0f / lrun;
#pragma unroll
  for (int dd = 0; dd < 8; ++dd) {
    uint2 o2;
    o2.x = cvtpk_bf16(acc[dd][0] * inv_l, acc[dd][1] * inv_l);
    o2.y = cvtpk_bf16(acc[dd][2] * inv_l, acc[dd][3] * inv_l);
    *(uint2*)(op + dd * 16 + quad * 4) = o2;
  }
}

extern "C" void kernel_launch(void* const* d_in, const int* in_sizes, int n_in,
                              void* d_out, int out_size, void* d_ws, size_t ws_size,
                              hipStream_t stream) {
  const float* hidden = (const float*)d_in[0];  // [2,2048,2048]
  const float* w_qkv = (const float*)d_in[1];   // [6144,2048]
  const float* w_out = (const float*)d_in[2];   // [2048,2048]
  float* out = (float*)d_out;                   // [2,2048,2048] fp32
  char* ws = (char*)d_ws;

  // workspace layout (112 MB total, all 16B aligned)
  u16* hid_b  = (u16*)(ws + (size_t)0);          // hidden bf16
  u16* wqkv_b = (u16*)(ws + (size_t)16777216);   // w_qkv bf16
  u16* wout_b = (u16*)(ws + (size_t)41943040);   // w_out bf16
  u16* qb     = (u16*)(ws + (size_t)50331648);   // q (unroped) [B,H,S,D]
  u16* kb     = (u16*)(ws + (size_t)67108864);   // k (roped)   [B,H,S,D]
  u16* vb     = (u16*)(ws + (size_t)83886080);   // v^T [B,H,D,S]
  u16* ao     = (u16*)(ws + (size_t)100663296);  // attn out [B,S,E]

  cast3_kernel<<<24576, 256, 0, stream>>>(hidden, hid_b, 2097152,
                                          w_qkv, wqkv_b, 3145728,
                                          w_out, wout_b, 1048576);

  // qkv projection, 128^2 R4 GEMM with fused split/transpose/k-rope epilogue
  gemm_bt_kernel<1><<<dim3(48, 32), 256, 0, stream>>>(hid_b, wqkv_b, 2048, 6144,
                                                      nullptr, qb, kb, vb);
  // causal flash attention (q-rope + scale in prologue), zero-shuffle P + cvt_pk
  attn_kernel<<<1024, 256, 0, stream>>>(qb, kb, vb, ao);
  // output projection -> fp32
  gemm_bt_kernel<0><<<dim3(16, 32), 256, 0, stream>>>(ao, wout_b, 2048, 2048,
                                                      out, nullptr, nullptr, nullptr);
}

// Round 9
// 373.817 us; speedup vs baseline: 1.1155x; 1.0199x over previous
//
#include <hip/hip_runtime.h>

typedef unsigned short u16;
typedef unsigned int u32;
typedef __attribute__((ext_vector_type(4))) float f32x4;
typedef __attribute__((ext_vector_type(8))) short s16x8;
typedef __attribute__((ext_vector_type(4))) unsigned int u32x4;

#define DEVI static __device__ __forceinline__

// B=2, S=2048, E=2048, H=16, D=128, MP=4, local=512; qkv cols: [q(512) v(512) k(512)] x4
// k-rope fused into QKV-GEMM epilogue; q-rope (+ (1/sqrt(128))*log2(e) scale) fused into
// attention prologue; softmax in exp2 domain.

#define ROPE_C (-13.287712379549449f / 32.0f)  // -log2(10000)/32
#define QSCALE 0.12751743f                     // log2(e)/sqrt(128)

DEVI u16 f2bf(float f) {
  u32 u = __float_as_uint(f);
  return (u16)((u + 0x7FFFu + ((u >> 16) & 1u)) >> 16);  // round-to-nearest-even
}
DEVI float bf2f(u16 h) { return __uint_as_float(((u32)h) << 16); }

DEVI void async_copy16(const u16* g, u16* l) {
  // dest = wave-uniform LDS base + lane*16 (gfx950 global_load_lds_dwordx4)
  __builtin_amdgcn_global_load_lds((__attribute__((address_space(1))) void*)g,
                                   (__attribute__((address_space(3))) void*)l, 16, 0, 0);
}

// fused fp32->bf16 cast of all three inputs
__global__ __launch_bounds__(256) void cast3_kernel(
    const float* __restrict__ s0, u16* __restrict__ d0, int n0,
    const float* __restrict__ s1, u16* __restrict__ d1, int n1,
    const float* __restrict__ s2, u16* __restrict__ d2, int n2) {
  int i = blockIdx.x * 256 + threadIdx.x;
  const float* s;
  u16* d;
  if (i < n0) {
    s = s0; d = d0;
  } else if (i < n0 + n1) {
    s = s1; d = d1; i -= n0;
  } else if (i < n0 + n1 + n2) {
    s = s2; d = d2; i -= n0 + n1;
  } else {
    return;
  }
  const float4 v = ((const float4*)s)[i];
  ushort4 o;
  o.x = f2bf(v.x); o.y = f2bf(v.y); o.z = f2bf(v.z); o.w = f2bf(v.w);
  ((ushort4*)d)[i] = o;
}

// C[m,n] = sum_k A[m,k]*B[n,k]; A,B row-major bf16, K contiguous (B^T GEMM).
// 128x128 tile, BK=32, 4 waves 2x2 of 64x64, 16x16x32 MFMA, 4x4 frags/wave.
// R4 structure (best measured, 136.5us QKV): A,B staged through 3-deep LDS via
// global_load_lds w16, XOR-swizzled, vmcnt(4) + raw s_barrier in steady state,
// 3 blocks/CU (cross-block overlap hides the barrier drains). Inline epilogue.
// EPI=0: C fp32 store. EPI=1: scatter qkv -> q[B,H,S,D], k(roped)[B,H,S,D], v^T[B,H,D,S].
template <int EPI>
__global__ __launch_bounds__(256, 3) void gemm_bt_kernel(
    const u16* __restrict__ A, const u16* __restrict__ Bm, int K, int N,
    float* __restrict__ C, u16* __restrict__ qo, u16* __restrict__ ko, u16* __restrict__ vo) {
  __shared__ __attribute__((aligned(16))) u16 As[3][128 * 32];  // 8KB each
  __shared__ __attribute__((aligned(16))) u16 Bs[3][128 * 32];  // 8KB each
  const int tid = threadIdx.x;
  const int w = tid >> 6, lane = tid & 63;
  const int quad = lane >> 4, l16 = lane & 15;
  const int wrow = (w >> 1) * 64, wcol = (w & 1) * 64;
  const long tileM = (long)blockIdx.y * 128;
  const long tileN = (long)blockIdx.x * 128;

  f32x4 acc[4][4];
#pragma unroll
  for (int i = 0; i < 4; ++i)
#pragma unroll
    for (int j = 0; j < 4; ++j) acc[i][j] = f32x4{0.f, 0.f, 0.f, 0.f};

  // staging: wave w covers tile rows [w*32, w*32+32) in two 16-row chunks.
  const u16* aptr[2];
  const u16* bptr[2];
  int ldso[2];
#pragma unroll
  for (int c = 0; c < 2; ++c) {
    const int r0 = (w * 2 + c) * 16;
    const int row = r0 + (lane >> 2);
    const int colsw = (((lane & 3) ^ ((row >> 1) & 3)) << 3);
    aptr[c] = A + (tileM + row) * (long)K + colsw;
    bptr[c] = Bm + (tileN + row) * (long)K + colsw;
    ldso[c] = r0 * 32;
  }

  auto stage = [&](int k0, int buf) {
#pragma unroll
    for (int c = 0; c < 2; ++c) {
      async_copy16(aptr[c] + k0, &As[buf][ldso[c]]);
      async_copy16(bptr[c] + k0, &Bs[buf][ldso[c]]);
    }
  };

  stage(0, 0);
  stage(32, 1);

  const int psw = (quad ^ ((l16 >> 1) & 3)) << 3;  // read-side swizzle (lane-constant)

  int bt = 0;
  for (int k0 = 0; k0 < K; k0 += 32) {
    if (k0 + 32 < K)
      __builtin_amdgcn_s_waitcnt(0x0f74);  // vmcnt(4): tile t landed, t+1 in flight
    else
      __builtin_amdgcn_s_waitcnt(0x0f70);  // last tile: vmcnt(0)
    __builtin_amdgcn_s_barrier();          // raw barrier: no compiler-forced drain
    if (k0 + 64 < K) stage(k0 + 64, bt == 0 ? 2 : bt - 1);

    s16x8 af[4], bfr[4];
#pragma unroll
    for (int i = 0; i < 4; ++i)
      af[i] = *(const s16x8*)(&As[bt][(wrow + i * 16 + l16) * 32 + psw]);
#pragma unroll
    for (int j = 0; j < 4; ++j)
      bfr[j] = *(const s16x8*)(&Bs[bt][(wcol + j * 16 + l16) * 32 + psw]);
#pragma unroll
    for (int i = 0; i < 4; ++i)
#pragma unroll
      for (int j = 0; j < 4; ++j)
        acc[i][j] = __builtin_amdgcn_mfma_f32_16x16x32_bf16(af[i], bfr[j], acc[i][j], 0, 0, 0);
    bt = bt == 2 ? 0 : bt + 1;
  }

  // ---- inline epilogue (single call site; acc stays in registers) ----
  const int b = (int)(tileM >> 11);  // 128-row tile never straddles batch
#pragma unroll
  for (int i = 0; i < 4; ++i) {
#pragma unroll
    for (int j = 0; j < 4; ++j) {
      const int rowb = (int)((tileM + wrow + i * 16 + quad * 4) & 2047);  // s of reg 0
      if (EPI == 0) {
#pragma unroll
        for (int r = 0; r < 4; ++r) {
          const long row = tileM + wrow + i * 16 + quad * 4 + r;
          C[row * N + tileN + wcol + j * 16 + l16] = acc[i][j][r];
        }
      } else {
        const long col0 = tileN + wcol + j * 16;  // wave-uniform base col of this frag
        const int mp = (int)(col0 / 1536);
        const int cc0 = (int)(col0 - (long)mp * 1536);
        const int part = cc0 >> 9;     // 0:q 1:v 2:k (uniform per frag)
        const int idx0 = cc0 & 511;
        const int head = mp * 4 + (idx0 >> 7);
        const int dim0 = idx0 & 127;
        const int dim = dim0 + l16;
        const long bh = (long)(b * 16 + head);
        if (part == 1) {
          // v^T: r-consecutive addresses -> one 8B store (f2bf pack; canary-neutral)
          uint2 o2;
          o2.x = (u32)f2bf(acc[i][j][0]) | ((u32)f2bf(acc[i][j][1]) << 16);
          o2.y = (u32)f2bf(acc[i][j][2]) | ((u32)f2bf(acc[i][j][3]) << 16);
          *(uint2*)(vo + (bh * 128 + dim) * 2048 + rowb) = o2;
        } else {
          float y[4];
          if (part == 2 && dim0 < 64) {
            // k-rope: pair partner is adjacent lane (col parity == l16 parity)
            const int jj = dim >> 1;
            const float inv = exp2f((float)jj * ROPE_C);
#pragma unroll
            for (int r = 0; r < 4; ++r) {
              const float v = acc[i][j][r];
              const float pv = __shfl_xor(v, 1, 64);
              const float ang = (float)(rowb + r) * inv;
              const float sn = __sinf(ang), cs = __cosf(ang);
              y[r] = (l16 & 1) ? (v * cs + pv * sn) : (v * cs - pv * sn);
            }
          } else {
#pragma unroll
            for (int r = 0; r < 4; ++r) y[r] = acc[i][j][r];
          }
          u16* dst = (part == 0) ? qo : ko;
#pragma unroll
          for (int r = 0; r < 4; ++r)
            dst[(bh * 2048 + rowb + r) * 128 + dim] = f2bf(y[r]);
        }
      }
    }
  }
}

// Flash attention v4.5 (= proven v4.3 structure + two critical-path cuts; cvt_pk
// REVERTED per R7 gate -- the inline asm cost ~7us vs f2bf).
// Block = 64 q rows (4 waves x 16 rows), 32-key tiles, 3-deep LDS ring + counted
// vmcnt(4) (4 DMAs/wave/tile). S^T = K*Q^T: each lane holds 8 scores of ONE q-row.
// Zero-shuffle P: K staged in PERMUTED row order so S^T C-layout == PV B-frag layout.
// v4.5 cuts:
//  (a) sm-defer: lrun is a per-lane PARTIAL sum (rescale by row-uniform alpha
//      commutes); cross-quad 2-shfl butterfly moved to the epilogue. Removes 2
//      dependent ds_bpermute per tile from the loop (sub-ulp sum reorder only).
//  (b) speculative P: p = exp2(sc - mrun_old) computed IN PARALLEL with the mx
//      2-shfl reduce; rare rescale branch (first tile / max growth >8) recomputes.
//      Safe: if any sc-mrun > 8 the branch provably triggers (mx >= sc), so used
//      speculative p <= 2^8; first-tile infs are discarded by the recompute.
// Keeps: setprio (T5), defer-max THR=8 (T13), QK^T g-interleave, raw s_barrier after
// explicit vmcnt. PV = V^T*P gives out^T; 8B stores. Heavy-first grid, 3 blocks/CU.
__global__ __launch_bounds__(256, 3) void attn_kernel(
    const u16* __restrict__ q, const u16* __restrict__ k,
    const u16* __restrict__ vT, u16* __restrict__ out) {
  __shared__ __attribute__((aligned(16))) u16 Ks[3][32 * 128];  // 8KB each
  __shared__ __attribute__((aligned(16))) u16 Vs[3][128 * 32];  // 8KB each
  const int tid = threadIdx.x;
  const int w = tid >> 6, lane = tid & 63;
  const int quad = lane >> 4, l16 = lane & 15;
  const int qt = 31 - (blockIdx.x >> 5);  // heavy tiles dispatched first
  const int bh = blockIdx.x & 31;
  const int qbase = qt * 64 + w * 16;

  const u16* qp = q + ((long)bh * 2048 + qbase) * 128;
  const u16* kp = k + (long)bh * 2048 * 128;
  const u16* vp = vT + (long)bh * 128 * 2048;

  // Q B-frag: Q[n=l16][kdim = c*32 + quad*8 + j], roped + scaled in fp32
  const float spos = (float)(qbase + l16);
  s16x8 qf[4];
#pragma unroll
  for (int c = 0; c < 4; ++c) {
    const s16x8 raw = *(const s16x8*)(qp + l16 * 128 + c * 32 + quad * 8);
    s16x8 ov;
    if (c < 2) {  // dims < 64: rotate pairs (in-lane: 2m, 2m+1)
#pragma unroll
      for (int m = 0; m < 4; ++m) {
        const int jj = c * 16 + quad * 4 + m;
        const float inv = exp2f((float)jj * ROPE_C);
        const float ang = spos * inv;
        const float sn = __sinf(ang), cs = __cosf(ang);
        const float x0 = bf2f((u16)raw[2 * m]), x1 = bf2f((u16)raw[2 * m + 1]);
        ov[2 * m] = (short)f2bf((x0 * cs - x1 * sn) * QSCALE);
        ov[2 * m + 1] = (short)f2bf((x1 * cs + x0 * sn) * QSCALE);
      }
    } else {      // dims >= 64: pass-through, scale only
#pragma unroll
      for (int e = 0; e < 8; ++e) ov[e] = (short)f2bf(bf2f((u16)raw[e]) * QSCALE);
    }
    qf[c] = ov;
  }

  f32x4 acc[8];  // out^T: acc[dd] rows = dims dd*16+quad*4+r, col = q-row l16
#pragma unroll
  for (int d = 0; d < 8; ++d) acc[d] = f32x4{0.f, 0.f, 0.f, 0.f};
  float mrun = -1e30f, lrun = 0.f;  // mrun row-uniform; lrun per-lane PARTIAL (v4.5a)

  // stage one 32-key tile: wave w stages LDS K-rows [w*8,w*8+8) and V dims
  // [w*32,w*32+32); exactly 4 async DMAs per wave per tile (vmcnt is per-wave).
  // K rows PERMUTED: LDS row rr holds global key ((rr>>2)&3)*8+((rr>>4)&1)*4+(rr&3).
  auto stage = [&](int k0, int buf) {
    const int ko = lane >> 4, cl = lane & 15;
#pragma unroll
    for (int i = 0; i < 2; ++i) {
      const int keyt = w * 8 + i * 4;
      const int rr = keyt + ko;  // LDS row this lane fills
      const int sk = ((rr >> 2) & 3) * 8 + ((rr >> 4) & 1) * 4 + (rr & 3);
      async_copy16(kp + (long)(k0 + sk) * 128 + ((cl ^ (rr & 15)) << 3),
                   &Ks[buf][keyt * 128]);
    }
    const int ld = lane >> 2, c4 = lane & 3;
#pragma unroll
    for (int i = 0; i < 2; ++i) {
      const int db = w * 32 + i * 16;
      const int d = db + ld;
      async_copy16(vp + (long)d * 2048 + k0 + ((c4 ^ ((d >> 1) & 3)) << 3),
                   &Vs[buf][db * 32]);
    }
  };

  const int nt = 2 * qt + 2;  // nt >= 2 always
  stage(0, 0);
  stage(32, 1);

  int bt = 0;
  for (int t = 0; t < nt; ++t) {
    const int k0 = t * 32;
    if (t + 1 < nt)
      __builtin_amdgcn_s_waitcnt(0x0f74);  // vmcnt(4): tile t landed, t+1 in flight
    else
      __builtin_amdgcn_s_waitcnt(0x0f70);  // last tile: vmcnt(0)
    __builtin_amdgcn_s_barrier();          // all waves' tile-t DMA done; buf t-1 free
    if (t + 2 < nt) stage(k0 + 64, bt == 0 ? 2 : bt - 1);
    const u16* Ksc = Ks[bt];
    const u16* Vsc = Vs[bt];

    // S^T = K*Q^T: sc[g] reg r at lane-quad u holds key k0 + u*8 + g*4 + r (permuted
    // staging), col = q-row l16. g interleaved inside c: consecutive MFMAs independent.
    f32x4 sc[2];
    sc[0] = f32x4{0.f, 0.f, 0.f, 0.f};
    sc[1] = f32x4{0.f, 0.f, 0.f, 0.f};
    __builtin_amdgcn_s_setprio(1);
#pragma unroll
    for (int c = 0; c < 4; ++c) {
      const s16x8 kf0 = *(const s16x8*)(
          &Ksc[(0 * 16 + l16) * 128 + ((((c << 2) + quad) ^ l16) << 3)]);
      const s16x8 kf1 = *(const s16x8*)(
          &Ksc[(1 * 16 + l16) * 128 + ((((c << 2) + quad) ^ l16) << 3)]);
      sc[0] = __builtin_amdgcn_mfma_f32_16x16x32_bf16(kf0, qf[c], sc[0], 0, 0, 0);
      sc[1] = __builtin_amdgcn_mfma_f32_16x16x32_bf16(kf1, qf[c], sc[1], 0, 0, 0);
    }
    __builtin_amdgcn_s_setprio(0);
    if (k0 + 31 > qbase) {  // tile may cross the diagonal (wave-uniform branch)
      const int qrow = qbase + l16;
#pragma unroll
      for (int g = 0; g < 2; ++g) {
        const int keyb = k0 + quad * 8 + g * 4;  // permuted key id of reg 0
#pragma unroll
        for (int r = 0; r < 4; ++r)
          if (keyb + r > qrow) sc[g][r] = -1e30f;
      }
    }
    // v4.5b: speculative P with OLD mrun, computed in parallel with the mx reduce.
    float mx = fmaxf(fmaxf(fmaxf(sc[0][0], sc[0][1]), fmaxf(sc[0][2], sc[0][3])),
                     fmaxf(fmaxf(sc[1][0], sc[1][1]), fmaxf(sc[1][2], sc[1][3])));
    mx = fmaxf(mx, __shfl_xor(mx, 16, 64));
    mx = fmaxf(mx, __shfl_xor(mx, 32, 64));
    float p[2][4];
#pragma unroll
    for (int g = 0; g < 2; ++g)
#pragma unroll
      for (int r = 0; r < 4; ++r) p[g][r] = exp2f(sc[g][r] - mrun);  // speculative
    if (__any(mx > mrun + 8.f)) {  // rare, wave-uniform: rescale + recompute
      const float mnew = fmaxf(mrun, mx);
      const float alpha = exp2f(mrun - mnew);
      mrun = mnew;
      lrun *= alpha;
#pragma unroll
      for (int d = 0; d < 8; ++d)
#pragma unroll
        for (int r = 0; r < 4; ++r) acc[d][r] *= alpha;
#pragma unroll
      for (int g = 0; g < 2; ++g)
#pragma unroll
        for (int r = 0; r < 4; ++r) p[g][r] = exp2f(sc[g][r] - mrun);
    }
    // v4.5a: per-lane partial sum only (cross-quad reduce deferred to epilogue)
    float sm = 0.f;
#pragma unroll
    for (int g = 0; g < 2; ++g)
#pragma unroll
      for (int r = 0; r < 4; ++r) sm += p[g][r];
    lrun += sm;

    // P -> PV B-frag, fully in-lane (permuted staging made C-layout == B-frag layout)
    u32 pk[2][2];
#pragma unroll
    for (int g = 0; g < 2; ++g) {
      pk[g][0] = (u32)f2bf(p[g][0]) | ((u32)f2bf(p[g][1]) << 16);
      pk[g][1] = (u32)f2bf(p[g][2]) | ((u32)f2bf(p[g][3]) << 16);
    }
    const u32x4 pw = {pk[0][0], pk[0][1], pk[1][0], pk[1][1]};
    const s16x8 pf = __builtin_bit_cast(s16x8, pw);

    // PV: out^T += V^T * P  (A = V^T[m=dim][k=key], B = P[n=qrow][k=key])
    __builtin_amdgcn_s_setprio(1);
#pragma unroll
    for (int dd = 0; dd < 8; ++dd) {
      const s16x8 vf = *(const s16x8*)(
          &Vsc[(dd * 16 + l16) * 32 + ((quad ^ ((l16 >> 1) & 3)) << 3)]);
      acc[dd] = __builtin_amdgcn_mfma_f32_16x16x32_bf16(vf, pf, acc[dd], 0, 0, 0);
    }
    __builtin_amdgcn_s_setprio(0);
    bt = bt == 2 ? 0 : bt + 1;
  }

  // epilogue: finish the deferred cross-quad l reduction, then store.
  lrun += __shfl_xor(lrun, 16, 64);
  lrun += __shfl_xor(lrun, 32, 64);
  const int b = bh >> 4, h = bh & 15;
  u16* op = out + ((long)b * 2048 + qbase + l16) * 2048 + h * 128;
  const float inv_l = 1.0f / lrun;
#pragma unroll
  for (int dd = 0; dd < 8; ++dd) {
    ushort4 o4;
    o4.x = f2bf(acc[dd][0] * inv_l);
    o4.y = f2bf(acc[dd][1] * inv_l);
    o4.z = f2bf(acc[dd][2] * inv_l);
    o4.w = f2bf(acc[dd][3] * inv_l);
    *(ushort4*)(op + dd * 16 + quad * 4) = o4;
  }
}

extern "C" void kernel_launch(void* const* d_in, const int* in_sizes, int n_in,
                              void* d_out, int out_size, void* d_ws, size_t ws_size,
                              hipStream_t stream) {
  const float* hidden = (const float*)d_in[0];  // [2,2048,2048]
  const float* w_qkv = (const float*)d_in[1];   // [6144,2048]
  const float* w_out = (const float*)d_in[2];   // [2048,2048]
  float* out = (float*)d_out;                   // [2,2048,2048] fp32
  char* ws = (char*)d_ws;

  // workspace layout (112 MB total, all 16B aligned)
  u16* hid_b  = (u16*)(ws + (size_t)0);          // hidden bf16
  u16* wqkv_b = (u16*)(ws + (size_t)16777216);   // w_qkv bf16
  u16* wout_b = (u16*)(ws + (size_t)41943040);   // w_out bf16
  u16* qb     = (u16*)(ws + (size_t)50331648);   // q (unroped) [B,H,S,D]
  u16* kb     = (u16*)(ws + (size_t)67108864);   // k (roped)   [B,H,S,D]
  u16* vb     = (u16*)(ws + (size_t)83886080);   // v^T [B,H,D,S]
  u16* ao     = (u16*)(ws + (size_t)100663296);  // attn out [B,S,E]

  cast3_kernel<<<24576, 256, 0, stream>>>(hidden, hid_b, 2097152,
                                          w_qkv, wqkv_b, 3145728,
                                          w_out, wout_b, 1048576);

  // qkv projection, 128^2 R4 GEMM with fused split/transpose/k-rope epilogue
  gemm_bt_kernel<1><<<dim3(48, 32), 256, 0, stream>>>(hid_b, wqkv_b, 2048, 6144,
                                                      nullptr, qb, kb, vb);
  // causal flash attention (q-rope + scale in prologue), zero-shuffle P,
  // sm-defer + speculative-P critical-path cuts
  attn_kernel<<<1024, 256, 0, stream>>>(qb, kb, vb, ao);
  // output projection -> fp32
  gemm_bt_kernel<0><<<dim3(16, 32), 256, 0, stream>>>(ao, wout_b, 2048, 2048,
                                                      out, nullptr, nullptr, nullptr);
}